// Round 1
// baseline (477.731 us; speedup 1.0000x reference)
//
#include <hip/hip_runtime.h>
#include <math.h>

#define B 32
#define C 1536
#define D2 3072
#define L 1024
#define KC 64      // k-chunk per staging pass (16 float4 quads)
#define CH 16      // flash L-chunks -> grid 16x32, 64 wave-partials per b
#define LPW 16     // l's per wave = L/(CH*4)

__device__ inline float dot4(float4 a, float4 b) {
    return a.x * b.x + a.y * b.y + a.z * b.z + a.w * b.w;
}
__device__ inline float4 ld4(const float* p) { return *(const float4*)p; }
__device__ inline void   st4(float* p, float4 v) { *(float4*)p = v; }

// swizzled LDS quad address (float index): row*KC + (q ^ ((row>>2)&7))*4
__device__ inline int sw(int row, int q) {
    return row * KC + ((q ^ ((row >> 2) & 7)) << 2);
}

// ---------------- init: pre-fill atomic-accumulated outputs with biases ----------------
// theta <- theta_b ; u <- 0 ; obuf <- gi_b ; o2 <- fc_b ; h <- fcn_b
__global__ __launch_bounds__(256) void init_k(float* __restrict__ theta, const float* __restrict__ tb,
                                              float* __restrict__ u,
                                              float* __restrict__ obuf, const float* __restrict__ gib,
                                              float* __restrict__ o2, const float* __restrict__ fcb,
                                              float* __restrict__ h, const float* __restrict__ fcnb) {
    int i = blockIdx.x * 256 + threadIdx.x;
    if (i < 32 * C) {
        int j = i % C;
        theta[i] = tb[j];
        u[i]     = 0.f;
        obuf[i]  = gib[j];
        o2[i]    = fcb[j];
    }
    if (i < 32 * D2) h[i] = fcnb[i % D2];
}

// ---------------- split-K GEMM: out += A @ W.T  (atomic accumulate) ----------------
// A: 32 x K row-major, W: N x K row-major. out pre-filled with bias.
__global__ __launch_bounds__(256) void gemm32(const float* __restrict__ A,
                                              const float* __restrict__ W,
                                              float* __restrict__ out,
                                              int N, int K, int kchunks) {
    __shared__ float xs[32 * KC];    // 8 KB
    __shared__ float wsm[64 * KC];   // 16 KB
    int tid = threadIdx.x;
    int j0 = blockIdx.x * 64;
    int kb = blockIdx.y;
    int tb = tid & 15;       // 16 b-groups of 2 rows
    int tj = tid >> 4;       // 16 j-groups of 4 cols

    float4 acc0 = make_float4(0.f, 0.f, 0.f, 0.f);
    float4 acc1 = make_float4(0.f, 0.f, 0.f, 0.f);

    for (int c = 0; c < kchunks; ++c) {
        int k0 = (kb * kchunks + c) * KC;
        __syncthreads();
        #pragma unroll
        for (int p = 0; p < 2; ++p) {
            int f = tid + 256 * p;
            int row = f >> 4, q = f & 15;
            st4(xs + sw(row, q), ld4(A + (size_t)row * K + k0 + 4 * q));
        }
        #pragma unroll
        for (int p = 0; p < 4; ++p) {
            int f = tid + 256 * p;
            int row = f >> 4, q = f & 15;
            st4(wsm + sw(row, q), ld4(W + (size_t)(j0 + row) * K + k0 + 4 * q));
        }
        __syncthreads();
        #pragma unroll
        for (int kq = 0; kq < 16; ++kq) {
            float4 x0 = ld4(xs + sw(2 * tb, kq));
            float4 x1 = ld4(xs + sw(2 * tb + 1, kq));
            float4 w0 = ld4(wsm + sw(4 * tj + 0, kq));
            float4 w1 = ld4(wsm + sw(4 * tj + 1, kq));
            float4 w2 = ld4(wsm + sw(4 * tj + 2, kq));
            float4 w3 = ld4(wsm + sw(4 * tj + 3, kq));
            acc0.x += dot4(x0, w0); acc0.y += dot4(x0, w1);
            acc0.z += dot4(x0, w2); acc0.w += dot4(x0, w3);
            acc1.x += dot4(x1, w0); acc1.y += dot4(x1, w1);
            acc1.z += dot4(x1, w2); acc1.w += dot4(x1, w3);
        }
    }
    float* p0 = out + (size_t)(2 * tb + 0) * N + j0 + 4 * tj;
    float* p1 = out + (size_t)(2 * tb + 1) * N + j0 + 4 * tj;
    atomicAdd(p0 + 0, acc0.x); atomicAdd(p0 + 1, acc0.y);
    atomicAdd(p0 + 2, acc0.z); atomicAdd(p0 + 3, acc0.w);
    atomicAdd(p1 + 0, acc1.x); atomicAdd(p1 + 1, acc1.y);
    atomicAdd(p1 + 2, acc1.z); atomicAdd(p1 + 3, acc1.w);
}

// ---------------- split-K GEMM, W stored k-major: out += A @ W ----------------
// A: 32 x K row-major, W: K x N row-major (reduction dim = row index).
// Transposes W tile through LDS during staging; compute loop identical to gemm32.
__global__ __launch_bounds__(256) void gemm32_nt(const float* __restrict__ A,
                                                 const float* __restrict__ W,
                                                 float* __restrict__ out,
                                                 int N, int K, int kchunks) {
    __shared__ float xs[32 * KC];
    __shared__ float wsm[64 * KC];
    int tid = threadIdx.x;
    int j0 = blockIdx.x * 64;
    int kb = blockIdx.y;
    int tb = tid & 15;
    int tj = tid >> 4;

    float4 acc0 = make_float4(0.f, 0.f, 0.f, 0.f);
    float4 acc1 = make_float4(0.f, 0.f, 0.f, 0.f);

    for (int c = 0; c < kchunks; ++c) {
        int k0 = (kb * kchunks + c) * KC;
        __syncthreads();
        #pragma unroll
        for (int p = 0; p < 2; ++p) {
            int f = tid + 256 * p;
            int row = f >> 4, q = f & 15;
            st4(xs + sw(row, q), ld4(A + (size_t)row * K + k0 + 4 * q));
        }
        // W tile: 64 k-rows x 64 j-cols, read coalesced along j, scatter to
        // wsm[j][k] (swizzled). 2-way bank aliasing at worst (free on CDNA4).
        #pragma unroll
        for (int p = 0; p < 4; ++p) {
            int f = tid + 256 * p;
            int r = f >> 4;          // k-row within tile
            int cq = f & 15;         // j-quad
            float4 v = ld4(W + (size_t)(k0 + r) * N + j0 + 4 * cq);
            wsm[sw(4 * cq + 0, r >> 2) + (r & 3)] = v.x;
            wsm[sw(4 * cq + 1, r >> 2) + (r & 3)] = v.y;
            wsm[sw(4 * cq + 2, r >> 2) + (r & 3)] = v.z;
            wsm[sw(4 * cq + 3, r >> 2) + (r & 3)] = v.w;
        }
        __syncthreads();
        #pragma unroll
        for (int kq = 0; kq < 16; ++kq) {
            float4 x0 = ld4(xs + sw(2 * tb, kq));
            float4 x1 = ld4(xs + sw(2 * tb + 1, kq));
            float4 w0 = ld4(wsm + sw(4 * tj + 0, kq));
            float4 w1 = ld4(wsm + sw(4 * tj + 1, kq));
            float4 w2 = ld4(wsm + sw(4 * tj + 2, kq));
            float4 w3 = ld4(wsm + sw(4 * tj + 3, kq));
            acc0.x += dot4(x0, w0); acc0.y += dot4(x0, w1);
            acc0.z += dot4(x0, w2); acc0.w += dot4(x0, w3);
            acc1.x += dot4(x1, w0); acc1.y += dot4(x1, w1);
            acc1.z += dot4(x1, w2); acc1.w += dot4(x1, w3);
        }
    }
    float* p0 = out + (size_t)(2 * tb + 0) * N + j0 + 4 * tj;
    float* p1 = out + (size_t)(2 * tb + 1) * N + j0 + 4 * tj;
    atomicAdd(p0 + 0, acc0.x); atomicAdd(p0 + 1, acc0.y);
    atomicAdd(p0 + 2, acc0.z); atomicAdd(p0 + 3, acc0.w);
    atomicAdd(p1 + 0, acc1.x); atomicAdd(p1 + 1, acc1.y);
    atomicAdd(p1 + 2, acc1.z); atomicAdd(p1 + 3, acc1.w);
}

// ---------------- split-K GEMM for fcn: A synthesized = [x | x + o2] ----------------
__global__ __launch_bounds__(256) void gemm32_h(const float* __restrict__ x,
                                                const float* __restrict__ o2,
                                                const float* __restrict__ W,   // D2 x D2
                                                float* __restrict__ out,
                                                int N, int K, int kchunks) {
    __shared__ float xs[32 * KC];
    __shared__ float wsm[64 * KC];
    int tid = threadIdx.x;
    int j0 = blockIdx.x * 64;
    int kb = blockIdx.y;
    int tb = tid & 15;
    int tj = tid >> 4;

    float4 acc0 = make_float4(0.f, 0.f, 0.f, 0.f);
    float4 acc1 = make_float4(0.f, 0.f, 0.f, 0.f);

    for (int c = 0; c < kchunks; ++c) {
        int k0 = (kb * kchunks + c) * KC;
        __syncthreads();
        #pragma unroll
        for (int p = 0; p < 2; ++p) {
            int f = tid + 256 * p;
            int row = f >> 4, q = f & 15;
            int kk = k0 + 4 * q;
            float4 v;
            if (kk < C) {
                v = ld4(x + (size_t)row * C + kk);
            } else {
                float4 a = ld4(x + (size_t)row * C + kk - C);
                float4 b = ld4(o2 + (size_t)row * C + kk - C);
                v = make_float4(a.x + b.x, a.y + b.y, a.z + b.z, a.w + b.w);
            }
            st4(xs + sw(row, q), v);
        }
        #pragma unroll
        for (int p = 0; p < 4; ++p) {
            int f = tid + 256 * p;
            int row = f >> 4, q = f & 15;
            st4(wsm + sw(row, q), ld4(W + (size_t)(j0 + row) * K + k0 + 4 * q));
        }
        __syncthreads();
        #pragma unroll
        for (int kq = 0; kq < 16; ++kq) {
            float4 x0 = ld4(xs + sw(2 * tb, kq));
            float4 x1 = ld4(xs + sw(2 * tb + 1, kq));
            float4 w0 = ld4(wsm + sw(4 * tj + 0, kq));
            float4 w1 = ld4(wsm + sw(4 * tj + 1, kq));
            float4 w2 = ld4(wsm + sw(4 * tj + 2, kq));
            float4 w3 = ld4(wsm + sw(4 * tj + 3, kq));
            acc0.x += dot4(x0, w0); acc0.y += dot4(x0, w1);
            acc0.z += dot4(x0, w2); acc0.w += dot4(x0, w3);
            acc1.x += dot4(x1, w0); acc1.y += dot4(x1, w1);
            acc1.z += dot4(x1, w2); acc1.w += dot4(x1, w3);
        }
    }
    float* p0 = out + (size_t)(2 * tb + 0) * N + j0 + 4 * tj;
    float* p1 = out + (size_t)(2 * tb + 1) * N + j0 + 4 * tj;
    atomicAdd(p0 + 0, acc0.x); atomicAdd(p0 + 1, acc0.y);
    atomicAdd(p0 + 2, acc0.z); atomicAdd(p0 + 3, acc0.w);
    atomicAdd(p1 + 0, acc1.x); atomicAdd(p1 + 1, acc1.y);
    atomicAdd(p1 + 2, acc1.z); atomicAdd(p1 + 3, acc1.w);
}

// ---------------- layernorm + relu over fully-accumulated o (bias included) ----------------
__global__ __launch_bounds__(256) void ln_relu(const float* __restrict__ obuf,
                                               const float* __restrict__ g,
                                               const float* __restrict__ bt,
                                               float* __restrict__ out) {
    int b = blockIdx.x, tid = threadIdx.x;
    __shared__ float r1[4], r2[4];
    float lv[6];
    float s1 = 0.f, s2 = 0.f;
    #pragma unroll
    for (int t = 0; t < 6; ++t) {
        int c = tid + 256 * t;
        float acc = obuf[(size_t)b * C + c];
        lv[t] = acc; s1 += acc; s2 += acc * acc;
    }
    #pragma unroll
    for (int off = 32; off > 0; off >>= 1) {
        s1 += __shfl_xor(s1, off, 64);
        s2 += __shfl_xor(s2, off, 64);
    }
    int wave = tid >> 6, lane = tid & 63;
    if (lane == 0) { r1[wave] = s1; r2[wave] = s2; }
    __syncthreads();
    s1 = r1[0] + r1[1] + r1[2] + r1[3];
    s2 = r2[0] + r2[1] + r2[2] + r2[3];
    float mu = s1 / (float)C;
    float var = s2 / (float)C - mu * mu;
    float rstd = 1.0f / sqrtf(var + 1e-5f);
    #pragma unroll
    for (int t = 0; t < 6; ++t) {
        int c = tid + 256 * t;
        float y = (lv[t] - mu) * rstd * g[c] + bt[c];
        out[(size_t)b * C + c] = fmaxf(y, 0.f);
    }
}

// ---------------- flash: scores + online softmax + weighted lfb accumulation ----------------
__global__ __launch_bounds__(256) void flash_k(const float* __restrict__ u,    // 32 x C
                                               const float* __restrict__ lfb,  // 32 x L x C
                                               float* __restrict__ pm,
                                               float* __restrict__ ps,
                                               float* __restrict__ pv) {
    int chunk = blockIdx.x;          // 0..CH-1
    int b = blockIdx.y;              // 0..31
    int wave = threadIdx.x >> 6;     // 0..3
    int lane = threadIdx.x & 63;
    int widx = chunk * 4 + wave;     // 0..63

    const float scale = 39.19183588453085f;  // sqrt(1536)

    float uu[24];
    const float* ub = u + (size_t)b * C;
    #pragma unroll
    for (int t = 0; t < 6; ++t)
        *(float4*)(uu + 4 * t) = ld4(ub + 4 * lane + 256 * t);

    float m = -INFINITY, s = 0.f;
    float vv[24];
    #pragma unroll
    for (int t = 0; t < 24; ++t) vv[t] = 0.f;

    int l0 = chunk * (L / CH) + wave;        // stride 4 within chunk
    for (int i = 0; i < LPW; ++i) {
        int l = l0 + i * 4;
        const float* row = lfb + ((size_t)b * L + l) * C;
        float xx[24];
        #pragma unroll
        for (int t = 0; t < 6; ++t)
            *(float4*)(xx + 4 * t) = ld4(row + 4 * lane + 256 * t);
        float d = 0.f;
        #pragma unroll
        for (int t = 0; t < 24; ++t) d += xx[t] * uu[t];
        #pragma unroll
        for (int off = 32; off > 0; off >>= 1) d += __shfl_xor(d, off, 64);
        float score = d * scale;
        float mn = fmaxf(m, score);
        float alpha = __expf(m - mn);        // 0 when m == -inf
        float p = __expf(score - mn);
        s = s * alpha + p;
        #pragma unroll
        for (int t = 0; t < 24; ++t) vv[t] = vv[t] * alpha + p * xx[t];
        m = mn;
    }

    if (lane == 0) { pm[b * 64 + widx] = m; ps[b * 64 + widx] = s; }
    float* pvb = pv + ((size_t)b * 64 + widx) * C;
    #pragma unroll
    for (int t = 0; t < 6; ++t)
        st4(pvb + 4 * lane + 256 * t, *(float4*)(vv + 4 * t));
}

// ---------------- combine wave-partials -> v[b][c] ----------------
__global__ __launch_bounds__(256) void combine_k(const float* __restrict__ pm,
                                                 const float* __restrict__ ps,
                                                 const float* __restrict__ pv,
                                                 float* __restrict__ v) {
    int cc = blockIdx.x;             // 0..5
    int b = blockIdx.y;              // 0..31
    int tid = threadIdx.x;
    __shared__ float coef[64];
    if (tid < 64) {
        float mj = pm[b * 64 + tid];
        float M = mj;
        #pragma unroll
        for (int off = 32; off > 0; off >>= 1) M = fmaxf(M, __shfl_xor(M, off, 64));
        float ej = expf(mj - M);
        float S = ps[b * 64 + tid] * ej;
        #pragma unroll
        for (int off = 32; off > 0; off >>= 1) S += __shfl_xor(S, off, 64);
        coef[tid] = ej / S;
    }
    __syncthreads();
    int c = cc * 256 + tid;
    float acc = 0.f;
    #pragma unroll 8
    for (int j = 0; j < 64; ++j)
        acc += coef[j] * pv[((size_t)b * 64 + j) * C + c];
    v[(size_t)b * C + c] = acc;
}

// ---------------- final: relu(h) + 4 head dots (h fully accumulated, bias in) ----------------
__global__ __launch_bounds__(256) void final_k(const float* __restrict__ h,    // 32 x D2
                                               const float* __restrict__ w1, const float* __restrict__ b1,
                                               const float* __restrict__ w2, const float* __restrict__ b2,
                                               const float* __restrict__ w3, const float* __restrict__ b3,
                                               const float* __restrict__ wt, const float* __restrict__ bt,
                                               float* __restrict__ out) {
    int b = blockIdx.x;
    int tid = threadIdx.x;
    float ph0 = 0.f, ph1 = 0.f, ph2 = 0.f, ptv = 0.f;
    #pragma unroll
    for (int t = 0; t < 12; ++t) {
        int j = tid + 256 * t;
        float s = fmaxf(h[(size_t)b * D2 + j], 0.f);
        ptv += s * wt[j];
        int jj = tid + 256 * (t & 3);
        if (t < 4)       ph0 += s * w1[jj];
        else if (t < 8)  ph1 += s * w2[jj];
        else             ph2 += s * w3[jj];
    }
    #pragma unroll
    for (int off = 32; off > 0; off >>= 1) {
        ph0 += __shfl_xor(ph0, off, 64);
        ph1 += __shfl_xor(ph1, off, 64);
        ph2 += __shfl_xor(ph2, off, 64);
        ptv += __shfl_xor(ptv, off, 64);
    }
    __shared__ float red[4][4];
    int wave = tid >> 6, lane = tid & 63;
    if (lane == 0) {
        red[wave][0] = ph0; red[wave][1] = ph1; red[wave][2] = ph2; red[wave][3] = ptv;
    }
    __syncthreads();
    if (tid < 4) {
        float v = red[0][tid] + red[1][tid] + red[2][tid] + red[3][tid];
        float bias = (tid == 0) ? b1[0] : (tid == 1) ? b2[0] : (tid == 2) ? b3[0] : bt[0];
        out[b * 4 + tid] = v + bias;
    }
}

extern "C" void kernel_launch(void* const* d_in, const int* in_sizes, int n_in,
                              void* d_out, int out_size, void* d_ws, size_t ws_size,
                              hipStream_t stream) {
    (void)in_sizes; (void)n_in; (void)out_size; (void)ws_size;
    const float* x       = (const float*)d_in[0];
    const float* lfb     = (const float*)d_in[1];
    const float* theta_w = (const float*)d_in[2];
    const float* theta_b = (const float*)d_in[3];
    const float* phi_w   = (const float*)d_in[4];
    // d_in[5] = phi_b: additive per-row constant in softmax -> drops out
    const float* gi_w    = (const float*)d_in[6];
    const float* gi_b    = (const float*)d_in[7];
    const float* ln_g    = (const float*)d_in[8];
    const float* ln_b    = (const float*)d_in[9];
    const float* fc_w    = (const float*)d_in[10];
    const float* fc_b    = (const float*)d_in[11];
    const float* fcn_w   = (const float*)d_in[12];
    const float* fcn_b   = (const float*)d_in[13];
    const float* w1 = (const float*)d_in[14]; const float* b1 = (const float*)d_in[15];
    const float* w2 = (const float*)d_in[16]; const float* b2 = (const float*)d_in[17];
    const float* w3 = (const float*)d_in[18]; const float* b3 = (const float*)d_in[19];
    const float* wt = (const float*)d_in[20]; const float* bt = (const float*)d_in[21];
    float* out = (float*)d_out;
    float* w = (float*)d_ws;

    // workspace layout (floats), all disjoint (~14 MB of workspace)
    float* pv    = w;                  // 3145728 (32 x 64 x C)
    float* pm    = w + 3145728;        // 2048
    float* ps    = w + 3147776;        // 2048
    float* theta = w + 3149824;        // 49152
    float* u     = w + 3198976;        // 49152
    float* vbuf  = w + 3248128;        // 49152
    float* obuf  = w + 3297280;        // 49152
    float* oln   = w + 3346432;        // 49152
    float* o2    = w + 3395584;        // 49152
    float* h     = w + 3444736;        // 98304 (32 x D2)

    // pre-fill accumulation targets with biases (replay/poison-safe: runs every launch)
    init_k<<<384, 256, 0, stream>>>(theta, theta_b, u, obuf, gi_b, o2, fc_b, h, fcn_b);

    // theta += x @ theta_w.T   (theta pre-filled with theta_b)
    gemm32<<<dim3(24, 12), 256, 0, stream>>>(x, theta_w, theta, C, C, 2);

    // u += theta @ phi_w       (phi_w read k-major; no transpose kernel)
    gemm32_nt<<<dim3(24, 12), 256, 0, stream>>>(theta, phi_w, u, C, C, 2);

    // flash over lfb
    flash_k<<<dim3(CH, B), 256, 0, stream>>>(u, lfb, pm, ps, pv);
    combine_k<<<dim3(6, B), 256, 0, stream>>>(pm, ps, pv, vbuf);

    // o += v @ gi_w.T (pre-filled with gi_b); then oln = relu(LN(o))
    gemm32<<<dim3(24, 12), 256, 0, stream>>>(vbuf, gi_w, obuf, C, C, 2);
    ln_relu<<<B, 256, 0, stream>>>(obuf, ln_g, ln_b, oln);

    // o2 += oln @ fc_w.T (pre-filled with fc_b)
    gemm32<<<dim3(24, 12), 256, 0, stream>>>(oln, fc_w, o2, C, C, 2);

    // h += [x | x + o2] @ fcn_w.T (pre-filled with fcn_b); feats never materialized
    gemm32_h<<<dim3(48, 12), 256, 0, stream>>>(x, o2, fcn_w, h, D2, D2, 4);

    // relu + 4 head dots
    final_k<<<B, 256, 0, stream>>>(h, w1, b1, w2, b2, w3, b3, wt, bt, out);
}